// Round 4
// baseline (269.362 us; speedup 1.0000x reference)
//
#include <hip/hip_runtime.h>
#include <hip/hip_bf16.h>
#include <hip/hip_fp16.h>

// Bahdanau attention: B=32, T=4096, QD=VD=AD=256
// out = (c [32,256], a [32,4096]) fp32, concatenated flat.
//
// Round 4: barrier-free single-wave blocks. Block = 1 wave = 32 t-rows.
// V staged once (coalesced f32x4 row loads -> f16 swizzled 16KB wave-private
// LDS). B-frags (values, t-cols) in 64 VGPRs. A-frags (Wv, a-rows) streamed
// from a pre-swizzled global frag table (128KB, L2-hot) with an 8-deep
// double buffer -- the K-loop is global_load+MFMA only, no LDS, no barriers.
// Epilogue: in-lane sum_a wv*tanh, exp (no max pass: |e|<=~3), P.V from the
// staged LDS tile, direct atomics.

#define BB 32
#define TT 4096
#define DD 256

typedef _Float16 half8  __attribute__((ext_vector_type(8)));
typedef _Float16 half4v __attribute__((ext_vector_type(4)));
typedef float f32x2  __attribute__((ext_vector_type(2)));
typedef float f32x4  __attribute__((ext_vector_type(4)));
typedef float f32x16 __attribute__((ext_vector_type(16)));

// 16B-group swizzle within a 512B row; measured conflict-free in round 3.
__device__ __forceinline__ int swz(int row, int g) {
    return g ^ (row & 7) ^ (((row >> 3) & 3) << 3);
}

__device__ __forceinline__ float tanh_fast(float x) {
    float ex = __expf(2.f*x);
    return __builtin_fmaf(-2.f, __builtin_amdgcn_rcpf(ex + 1.f), 1.f);
}

// ---------------------------------------------------------------------------
// Kernel 0: prep.
//  blocks 0..31 : qw[b,a] = { query[b,:].Wq[a,:] + bq[a] + bv[a], wvs[a] }
//  blocks 32..63: Wv fp32 -> f16 A-fragment table:
//    wvA[(at*16 + kk)*64 + L] = half8{ Wv[a][k] }, a = at*32 + (L&31),
//    k = kk*16 + (L>>5)*8 + j   (layout validated rounds 1-3)
// ---------------------------------------------------------------------------
__global__ __launch_bounds__(256) void prep_kernel(
    const float* __restrict__ query, const float* __restrict__ Wq,
    const float* __restrict__ bq,    const float* __restrict__ Wv,
    const float* __restrict__ bv,    const float* __restrict__ wvs,
    f32x2* __restrict__ qw, half8* __restrict__ wvA)
{
    int blk = blockIdx.x, tid = threadIdx.x;
    if (blk < BB) {
        __shared__ float ql[DD];
        ql[tid] = query[blk*DD + tid];
        __syncthreads();
        const f32x4* wr4 = (const f32x4*)(Wq + tid*DD);
        const f32x4* ql4 = (const f32x4*)ql;
        float s = 0.f;
        #pragma unroll 8
        for (int q = 0; q < DD/4; ++q) {
            f32x4 w4 = wr4[q];
            f32x4 x4 = ql4[q];
            s += w4[0]*x4[0] + w4[1]*x4[1] + w4[2]*x4[2] + w4[3]*x4[3];
        }
        f32x2 o;
        o[0] = s + bq[tid] + bv[tid];
        o[1] = wvs[tid];
        qw[blk*DD + tid] = o;
    } else {
        int idx = (blk - BB)*256 + tid;      // 0..8191
        int a    = ((idx >> 10) << 5) + (idx & 31);       // at*32 + tl
        int koff = (((idx >> 6) & 15) << 4) + (((idx >> 5) & 1) << 3);
        const float* src = Wv + a*DD + koff;
        f32x4 s0 = *(const f32x4*)(src);
        f32x4 s1 = *(const f32x4*)(src + 4);
        half8 h;
        h[0]=(_Float16)s0[0]; h[1]=(_Float16)s0[1]; h[2]=(_Float16)s0[2]; h[3]=(_Float16)s0[3];
        h[4]=(_Float16)s1[0]; h[5]=(_Float16)s1[1]; h[6]=(_Float16)s1[2]; h[7]=(_Float16)s1[3];
        wvA[idx] = h;
    }
}

// ---------------------------------------------------------------------------
// Kernel 1: fused. 4096 blocks x 64 threads (1 wave = 32 t-rows). No barriers.
// ---------------------------------------------------------------------------
__global__ __launch_bounds__(64, 2) void fused_kernel(
    const float* __restrict__ values, const half8* __restrict__ wvA,
    const f32x2* __restrict__ qw,     const float* __restrict__ bvs,
    float* __restrict__ p_out,        float* __restrict__ cout,
    float* __restrict__ Ssum)
{
    __shared__ char Vl[16384];           // 32 rows x 512B f16, swizzled

    int L  = threadIdx.x;                // 0..63
    int tl = L & 31, kh = L >> 5;
    int row0 = blockIdx.x * 32;          // global t-row (b*TT + t)
    int b    = blockIdx.x >> 7;          // 128 blocks per batch

    // ---- stage V: 32 rows x 1KB, one coalesced f32x4 row-load per inst.
    const float* gv = values + (size_t)row0 * DD + L*4;
    f32x4 ld[32];
    #pragma unroll
    for (int i = 0; i < 32; ++i)
        ld[i] = *(const f32x4*)(gv + i*DD);
    #pragma unroll
    for (int i = 0; i < 32; ++i) {
        half4v h;
        h[0]=(_Float16)ld[i][0]; h[1]=(_Float16)ld[i][1];
        h[2]=(_Float16)ld[i][2]; h[3]=(_Float16)ld[i][3];
        *(half4v*)(Vl + i*512 + swz(i, L >> 1)*16 + (L & 1)*8) = h;
    }
    __syncthreads();                     // single wave: just a waitcnt fence

    // ---- B-frags (this wave's 32 t-rows), resident in 64 VGPRs
    half8 bf[16];
    #pragma unroll
    for (int kk = 0; kk < 16; ++kk)
        bf[kk] = *(const half8*)(Vl + tl*512 + swz(tl, kk*2 + kh)*16);

    // ---- K-loop over 8 a-tiles; A-frags streamed from global (L2-hot),
    //      8-deep double buffer.
    const half8* wa = wvA + L;
    half8 afA[8], afB[8];
    #pragma unroll
    for (int g = 0; g < 8; ++g) afA[g] = wa[g*64];

    float e_acc = 0.f;
    const f32x2* qwb = qw + b*DD;

    #pragma unroll
    for (int at = 0; at < 8; ++at) {
        #pragma unroll
        for (int g = 0; g < 8; ++g) afB[g] = wa[(at*16 + 8 + g)*64];
        f32x16 acc = {};
        #pragma unroll
        for (int kk = 0; kk < 8; ++kk)
            acc = __builtin_amdgcn_mfma_f32_32x32x16_f16(afA[kk], bf[kk], acc, 0, 0, 0);
        if (at < 7) {
            #pragma unroll
            for (int g = 0; g < 8; ++g) afA[g] = wa[((at+1)*16 + g)*64];
        }
        #pragma unroll
        for (int kk = 0; kk < 8; ++kk)
            acc = __builtin_amdgcn_mfma_f32_32x32x16_f16(afB[kk], bf[8+kk], acc, 0, 0, 0);

        // in-lane epilogue: e += wv[a] * tanh(K[a][t] + qp[a]);  t = tl
        #pragma unroll
        for (int r = 0; r < 16; ++r) {
            int a = at*32 + (r & 3) + 8*(r >> 2) + 4*kh;
            f32x2 q2 = qwb[a];
            e_acc += q2[1] * tanh_fast(acc[r] + q2[0]);
        }
    }

    // ---- combine kh halves, p = exp(e) (|e| <= ~3), Ssum
    e_acc += __shfl_xor(e_acc, 32);
    float p = __expf(e_acc + bvs[0]);
    if (kh == 0) p_out[row0 + tl] = p;
    float s = p;
    s += __shfl_xor(s, 1);
    s += __shfl_xor(s, 2);
    s += __shfl_xor(s, 4);
    s += __shfl_xor(s, 8);
    s += __shfl_xor(s, 16);
    if (L == 0) atomicAdd(&Ssum[b], s);

    // ---- P.V from the staged tile: lane L owns vd = L*4..+4
    f32x4 cw = {};
    #pragma unroll
    for (int t2 = 0; t2 < 32; ++t2) {
        float pt = __shfl(p, t2);
        half4v v4 = *(const half4v*)(Vl + t2*512 + swz(t2, L >> 1)*16 + (L & 1)*8);
        cw[0] += pt*(float)v4[0]; cw[1] += pt*(float)v4[1];
        cw[2] += pt*(float)v4[2]; cw[3] += pt*(float)v4[3];
    }
    #pragma unroll
    for (int j = 0; j < 4; ++j)
        atomicAdd(&cout[b*DD + L*4 + j], cw[j]);
}

// ---------------------------------------------------------------------------
// Kernel 2: normalize. blocks 0..31: a[b,:] /= S[b]; block 32: c /= S[b].
// ---------------------------------------------------------------------------
__global__ __launch_bounds__(256) void finalize_kernel(
    float* __restrict__ out_c, float* __restrict__ out_a,
    const float* __restrict__ Ssum)
{
    int blk = blockIdx.x, tid = threadIdx.x;
    if (blk < BB) {
        float inv = 1.f / Ssum[blk];
        f32x4* ap = (f32x4*)(out_a + blk*TT);
        #pragma unroll
        for (int i = 0; i < 4; ++i) {
            f32x4 v = ap[i*256 + tid];
            v[0]*=inv; v[1]*=inv; v[2]*=inv; v[3]*=inv;
            ap[i*256 + tid] = v;
        }
    } else {
        f32x4* cp = (f32x4*)out_c;
        #pragma unroll
        for (int i = 0; i < 8; ++i) {
            int idx = i*256 + tid;       // f32x4 index, 64 per batch
            float inv = 1.f / Ssum[idx >> 6];
            f32x4 v = cp[idx];
            v[0]*=inv; v[1]*=inv; v[2]*=inv; v[3]*=inv;
            cp[idx] = v;
        }
    }
}

// ---------------------------------------------------------------------------
extern "C" void kernel_launch(void* const* d_in, const int* in_sizes, int n_in,
                              void* d_out, int out_size, void* d_ws, size_t ws_size,
                              hipStream_t stream)
{
    (void)in_sizes; (void)n_in; (void)out_size; (void)ws_size;
    const float* query  = (const float*)d_in[0];
    const float* values = (const float*)d_in[1];
    const float* Wq     = (const float*)d_in[2];
    const float* bq     = (const float*)d_in[3];
    const float* Wv     = (const float*)d_in[4];
    const float* bv     = (const float*)d_in[5];
    const float* wvs    = (const float*)d_in[6];
    const float* bvs    = (const float*)d_in[7];

    float* out  = (float*)d_out;
    float* cptr = out;             // [32,256]
    float* aptr = out + BB*DD;     // [32,4096] (unnormalized p, then a)

    f32x2* qw   = (f32x2*)d_ws;                              // 64 KB
    half8* wvA  = (half8*)((char*)d_ws + 65536);             // 128 KB
    float* Ssum = (float*)((char*)d_ws + 65536 + 131072);    // 128 B

    hipMemsetAsync(cptr, 0, BB*DD*sizeof(float), stream);
    hipMemsetAsync(Ssum, 0, BB*sizeof(float), stream);
    prep_kernel<<<64, 256, 0, stream>>>(query, Wq, bq, Wv, bv, wvs, qw, wvA);
    fused_kernel<<<TT*BB/32, 64, 0, stream>>>(values, wvA, qw, bvs,
                                              aptr, cptr, Ssum);
    finalize_kernel<<<BB + 1, 256, 0, stream>>>(cptr, aptr, Ssum);
}

// Round 5
// 222.010 us; speedup vs baseline: 1.2133x; 1.2133x over previous
//
#include <hip/hip_runtime.h>
#include <hip/hip_bf16.h>
#include <hip/hip_fp16.h>

// Bahdanau attention: B=32, T=4096, QD=VD=AD=256
// out = (c [32,256], a [32,4096]) fp32, concatenated flat.
//
// Round 5: m97-shaped throughput kernel, zero global atomics.
// 256 blocks (1/CU) x 512 threads (8 waves) x 16 tiles of 32 t-rows.
// Wave w holds Wv A-frags for a-slice [32w,+32) in 64 VGPRs (loaded once).
// Per tile: 1 coalesced f32x4 load/lane (prefetched 1 tile ahead), cvt->f16
// into dbuf swizzled LDS; 16 ds_read_b128 + MFMA; in-lane tanh epilogue;
// cross-wave e-combine in LDS; p + P.V wave-local. Block partials (c, sum p)
// stored to workspace; finalize reduces. No atomics anywhere.

#define BB 32
#define TT 4096
#define DD 256
#define NTILE 16          // tiles per block
#define TROWS 32          // t-rows per tile

typedef _Float16 half8  __attribute__((ext_vector_type(8)));
typedef _Float16 half4v __attribute__((ext_vector_type(4)));
typedef float f32x2  __attribute__((ext_vector_type(2)));
typedef float f32x4  __attribute__((ext_vector_type(4)));
typedef float f32x16 __attribute__((ext_vector_type(16)));

// 16B-group swizzle within a 512B row; measured conflict-free (R3/R4).
__device__ __forceinline__ int swz(int row, int g) {
    return g ^ (row & 7) ^ (((row >> 3) & 3) << 3);
}

__device__ __forceinline__ float tanh_fast(float x) {
    float ex = __expf(2.f*x);
    return __builtin_fmaf(-2.f, __builtin_amdgcn_rcpf(ex + 1.f), 1.f);
}

// ---------------------------------------------------------------------------
// Kernel 0: prep (unchanged from R4, layouts verified).
//  blocks 0..31 : qw[b,a] = { query[b,:].Wq[a,:] + bq[a] + bv[a], wvs[a] }
//  blocks 32..63: Wv fp32 -> f16 A-fragment table:
//    wvA[(at*16 + kk)*64 + L] = half8{ Wv[a][k] }, a = at*32 + (L&31),
//    k = kk*16 + (L>>5)*8 + j
// ---------------------------------------------------------------------------
__global__ __launch_bounds__(256) void prep_kernel(
    const float* __restrict__ query, const float* __restrict__ Wq,
    const float* __restrict__ bq,    const float* __restrict__ Wv,
    const float* __restrict__ bv,    const float* __restrict__ wvs,
    f32x2* __restrict__ qw, half8* __restrict__ wvA)
{
    int blk = blockIdx.x, tid = threadIdx.x;
    if (blk < BB) {
        __shared__ float ql[DD];
        ql[tid] = query[blk*DD + tid];
        __syncthreads();
        const f32x4* wr4 = (const f32x4*)(Wq + tid*DD);
        const f32x4* ql4 = (const f32x4*)ql;
        float s = 0.f;
        #pragma unroll 8
        for (int q = 0; q < DD/4; ++q) {
            f32x4 w4 = wr4[q];
            f32x4 x4 = ql4[q];
            s += w4[0]*x4[0] + w4[1]*x4[1] + w4[2]*x4[2] + w4[3]*x4[3];
        }
        f32x2 o;
        o[0] = s + bq[tid] + bv[tid];
        o[1] = wvs[tid];
        qw[blk*DD + tid] = o;
    } else {
        int idx = (blk - BB)*256 + tid;      // 0..8191
        int a    = ((idx >> 10) << 5) + (idx & 31);
        int koff = (((idx >> 6) & 15) << 4) + (((idx >> 5) & 1) << 3);
        const float* src = Wv + a*DD + koff;
        f32x4 s0 = *(const f32x4*)(src);
        f32x4 s1 = *(const f32x4*)(src + 4);
        half8 h;
        h[0]=(_Float16)s0[0]; h[1]=(_Float16)s0[1]; h[2]=(_Float16)s0[2]; h[3]=(_Float16)s0[3];
        h[4]=(_Float16)s1[0]; h[5]=(_Float16)s1[1]; h[6]=(_Float16)s1[2]; h[7]=(_Float16)s1[3];
        wvA[idx] = h;
    }
}

// ---------------------------------------------------------------------------
// Kernel 1: fused. 256 blocks x 512 threads. Block covers 512 t-rows.
// ---------------------------------------------------------------------------
__global__ __launch_bounds__(512, 2) void fused_kernel(
    const float* __restrict__ values, const half8* __restrict__ wvA,
    const f32x2* __restrict__ qw,     const float* __restrict__ bvs,
    float* __restrict__ p_out,        float* __restrict__ ws_cpart,
    float* __restrict__ ws_ssum)
{
    __shared__ char  Vl[2][16384];       // dbuf: 32 rows x 512B f16, swizzled
    __shared__ float ew[2][TROWS][8];    // e-partials [dbuf][t][wave]
    __shared__ float pbuf[512];          // unnormalized p for the block
    __shared__ f32x4 cbuf[8][64];        // per-wave c partials

    int tid = threadIdx.x;
    int w = tid >> 6;                    // wave 0..7 = a-slice
    int L = tid & 63;
    int tl = L & 31, kh = L >> 5;
    int blk = blockIdx.x;
    int row0 = blk * (NTILE*TROWS);      // 512 rows per block, all same b
    int b = row0 >> 12;

    // Wv A-frags for a-slice w: 64 VGPRs, loaded once (L2-hot table).
    half8 af[16];
    #pragma unroll
    for (int kk = 0; kk < 16; ++kk)
        af[kk] = wvA[(w*16 + kk)*64 + L];

    const f32x2* qwb = qw + b*DD;
    float bv0 = bvs[0];
    const float* gv = values + (size_t)row0 * DD;

    // prefetch tile 0: wave w stages local rows 4w..4w+3; one row per load.
    f32x4 ld[4];
    #pragma unroll
    for (int j = 0; j < 4; ++j)
        ld[j] = *(const f32x4*)(gv + (w*4 + j)*DD + L*4);

    f32x4 cw = {};
    float psum = 0.f;

    for (int tile = 0; tile < NTILE; ++tile) {
        char* Vb = Vl[tile & 1];
        // write staged rows (cvt f32->f16, swizzled; R4-verified pattern)
        #pragma unroll
        for (int j = 0; j < 4; ++j) {
            int r = w*4 + j;
            half4v h;
            h[0]=(_Float16)ld[j][0]; h[1]=(_Float16)ld[j][1];
            h[2]=(_Float16)ld[j][2]; h[3]=(_Float16)ld[j][3];
            *(half4v*)(Vb + r*512 + swz(r, L >> 1)*16 + (L & 1)*8) = h;
        }
        // prefetch next tile
        if (tile + 1 < NTILE) {
            const float* gn = gv + (size_t)(tile + 1)*TROWS*DD;
            #pragma unroll
            for (int j = 0; j < 4; ++j)
                ld[j] = *(const f32x4*)(gn + (w*4 + j)*DD + L*4);
        }
        __syncthreads();                 // staged tile visible

        // 16 k-steps: B-frag (values) from LDS, MFMA vs resident Wv frags
        f32x16 acc = {};
        #pragma unroll
        for (int kk = 0; kk < 16; ++kk) {
            half8 bf = *(const half8*)(Vb + tl*512 + swz(tl, kk*2 + kh)*16);
            acc = __builtin_amdgcn_mfma_f32_32x32x16_f16(af[kk], bf, acc, 0, 0, 0);
        }

        // in-lane epilogue over this wave's 32 a's (R4-verified row map)
        float e_acc = 0.f;
        #pragma unroll
        for (int r = 0; r < 16; ++r) {
            int a = w*32 + (r & 3) + 8*(r >> 2) + 4*kh;
            f32x2 q2 = qwb[a];
            e_acc += q2[1] * tanh_fast(acc[r] + q2[0]);
        }
        e_acc += __shfl_xor(e_acc, 32);  // combine kh halves
        if (L < 32) ew[tile & 1][tl][w] = e_acc;
        __syncthreads();                 // all e-partials visible

        // wave w finishes e for ITS OWN rows t = 4w..4w+3 (the rows it staged)
        float p = 0.f;
        if (L < 32) {
            float v = ew[tile & 1][4*w + (L >> 3)][L & 7];
            v += __shfl_xor(v, 1);
            v += __shfl_xor(v, 2);
            v += __shfl_xor(v, 4);
            if ((L & 7) == 0) {
                p = __expf(v + bv0);     // |e| <= ~3: no max pass needed
                pbuf[tile*TROWS + 4*w + (L >> 3)] = p;
            }
        }
        float pt0 = __shfl(p, 0);
        float pt1 = __shfl(p, 8);
        float pt2 = __shfl(p, 16);
        float pt3 = __shfl(p, 24);
        psum += pt0 + pt1 + pt2 + pt3;

        // P.V for own rows: lane L owns vd = 4L..4L+3
        #pragma unroll
        for (int j = 0; j < 4; ++j) {
            int r = w*4 + j;
            float pt = (j == 0) ? pt0 : (j == 1) ? pt1 : (j == 2) ? pt2 : pt3;
            half4v v4 = *(const half4v*)(Vb + r*512 + swz(r, L >> 1)*16 + (L & 1)*8);
            cw[0] += pt*(float)v4[0]; cw[1] += pt*(float)v4[1];
            cw[2] += pt*(float)v4[2]; cw[3] += pt*(float)v4[3];
        }
    }

    // ---- block epilogue: no atomics, plain stores to workspace ----
    cbuf[w][L] = cw;
    __syncthreads();
    // sum-p partials per wave -> ws_ssum[blk]
    float* sred = (float*)ew;
    if (L == 0) sred[w] = psum;
    __syncthreads();
    if (tid == 0) {
        float s = sred[0]+sred[1]+sred[2]+sred[3]+sred[4]+sred[5]+sred[6]+sred[7];
        ws_ssum[blk] = s;
    }
    // c partial: 64 threads reduce 8 wave-partials each
    if (tid < 64) {
        f32x4 tot = cbuf[0][tid];
        #pragma unroll
        for (int k = 1; k < 8; ++k) {
            f32x4 t2 = cbuf[k][tid];
            tot[0]+=t2[0]; tot[1]+=t2[1]; tot[2]+=t2[2]; tot[3]+=t2[3];
        }
        *(f32x4*)(ws_cpart + blk*DD + tid*4) = tot;
    }
    // coalesced unnormalized-p write
    p_out[row0 + tid] = pbuf[tid];
}

// ---------------------------------------------------------------------------
// Kernel 2: finalize. 32 blocks (one per batch) x 256 threads.
// Ssum[b] = sum of 8 block partials; c = sum partials / S; a = p / S.
// ---------------------------------------------------------------------------
__global__ __launch_bounds__(256) void finalize_kernel(
    float* __restrict__ out_c, float* __restrict__ out_a,
    const float* __restrict__ ws_cpart, const float* __restrict__ ws_ssum)
{
    int b = blockIdx.x, tid = threadIdx.x;
    __shared__ float sred[8];
    if (tid < 8) sred[tid] = ws_ssum[b*8 + tid];
    __syncthreads();
    float S = sred[0]+sred[1]+sred[2]+sred[3]+sred[4]+sred[5]+sred[6]+sred[7];
    float inv = 1.f / S;

    // c
    float tot = 0.f;
    #pragma unroll
    for (int k = 0; k < 8; ++k)
        tot += ws_cpart[(b*8 + k)*DD + tid];
    out_c[b*DD + tid] = tot * inv;

    // a = p * inv
    f32x4* ap = (f32x4*)(out_a + b*TT);
    #pragma unroll
    for (int i = 0; i < 4; ++i) {
        f32x4 v = ap[i*256 + tid];
        v[0]*=inv; v[1]*=inv; v[2]*=inv; v[3]*=inv;
        ap[i*256 + tid] = v;
    }
}

// ---------------------------------------------------------------------------
extern "C" void kernel_launch(void* const* d_in, const int* in_sizes, int n_in,
                              void* d_out, int out_size, void* d_ws, size_t ws_size,
                              hipStream_t stream)
{
    (void)in_sizes; (void)n_in; (void)out_size; (void)ws_size;
    const float* query  = (const float*)d_in[0];
    const float* values = (const float*)d_in[1];
    const float* Wq     = (const float*)d_in[2];
    const float* bq     = (const float*)d_in[3];
    const float* Wv     = (const float*)d_in[4];
    const float* bv     = (const float*)d_in[5];
    const float* wvs    = (const float*)d_in[6];
    const float* bvs    = (const float*)d_in[7];

    float* out  = (float*)d_out;
    float* cptr = out;             // [32,256]
    float* aptr = out + BB*DD;     // [32,4096] (unnormalized p, then a)

    char* ws = (char*)d_ws;
    f32x2* qw       = (f32x2*)ws;                 // 64 KB
    half8* wvA      = (half8*)(ws + 65536);       // 128 KB
    float* ws_cpart = (float*)(ws + 65536 + 131072);          // 256 KB
    float* ws_ssum  = (float*)(ws + 65536 + 131072 + 262144); // 1 KB

    prep_kernel<<<64, 256, 0, stream>>>(query, Wq, bq, Wv, bv, wvs, qw, wvA);
    fused_kernel<<<256, 512, 0, stream>>>(values, wvA, qw, bvs,
                                          aptr, ws_cpart, ws_ssum);
    finalize_kernel<<<BB, 256, 0, stream>>>(cptr, aptr, ws_cpart, ws_ssum);
}